// Round 2
// baseline (9637.819 us; speedup 1.0000x reference)
//
#include <hip/hip_runtime.h>
#include <stdint.h>

typedef __attribute__((ext_vector_type(8))) short short8;
typedef __attribute__((ext_vector_type(4))) float f32x4;

#define NW 16  // workgroups per direction in recurrent kernel

// ---- workspace byte offsets (total ~141.8 MB) ----
#define XB16_OFF  0UL           // bf16 layer input/output [t*64+b][512]   32 MB
#define XP_OFF    33554432UL    // fp16 projections [t*64+b][1536]         96 MB
#define WT_OFF    134217728UL   // bf16 W^T  [3][1536][512]               4.5 MB
#define UT_OFF    138936320UL   // bf16 U^T  [dir*3+l][768][256]         2.25 MB
#define BIASC_OFF 141295616UL   // fp32 input bias [3][1536]
#define BRC_OFF   141314048UL   // fp32 recur bias [dir*3+l][768]
#define H32_OFF   141332480UL   // fp32 h state [dir][buf][64*256]
#define HB16_OFF  141594624UL   // bf16 h state [dir][buf][64*256]
#define BAR_OFF   141725696UL   // 6 barrier counters
#define FLAG_OFF  141725760UL   // mask-dtype flag

// ---- threefry2x32, 20 rounds (matches jax._src.prng, partitionable mode) ----
__host__ __device__ static inline void tf2x32(unsigned k0, unsigned k1,
                                              unsigned x0, unsigned x1,
                                              unsigned* o0, unsigned* o1) {
  unsigned ks2 = k0 ^ k1 ^ 0x1BD11BDAu;
#define TFR(r) { x0 += x1; x1 = (x1 << (r)) | (x1 >> (32 - (r))); x1 ^= x0; }
  x0 += k0; x1 += k1;
  TFR(13) TFR(15) TFR(26) TFR(6)   x0 += k1;  x1 += ks2 + 1u;
  TFR(17) TFR(29) TFR(16) TFR(24)  x0 += ks2; x1 += k0 + 2u;
  TFR(13) TFR(15) TFR(26) TFR(6)   x0 += k0;  x1 += k1 + 3u;
  TFR(17) TFR(29) TFR(16) TFR(24)  x0 += k1;  x1 += ks2 + 4u;
  TFR(13) TFR(15) TFR(26) TFR(6)   x0 += ks2; x1 += k0 + 5u;
#undef TFR
  *o0 = x0; *o1 = x1;
}

__device__ static inline short f2bf(float f) {  // RNE fp32->bf16
  unsigned u = __float_as_uint(f);
  u = (u + 0x7fffu + ((u >> 16) & 1u)) >> 16;
  return (short)u;
}
__device__ static inline float bf2f(short s) {
  unsigned u = ((unsigned)(unsigned short)s) << 16;
  return __uint_as_float(u);
}

// ---- init: zero barrier counters + mask flag ----
__global__ void init_k(unsigned* bars, unsigned* flag) {
  if (threadIdx.x < 6) bars[threadIdx.x] = 0u;
  else if (threadIdx.x == 6) *flag = 0u;
}

// ---- prep: casts, transposes, tail copy, mask dtype detection ----
__global__ __launch_bounds__(256) void prep_k(
    const float* __restrict__ states, const unsigned* __restrict__ maskw,
    const float* __restrict__ Wf, const float* __restrict__ Uf,
    const float* __restrict__ bf_, const float* __restrict__ Wb,
    const float* __restrict__ Ub, const float* __restrict__ bb_,
    short* __restrict__ xb16, float* __restrict__ dout,
    short* __restrict__ Wt, short* __restrict__ Ut,
    float* __restrict__ biasc, float* __restrict__ brc,
    unsigned* __restrict__ flag) {
  const unsigned gid = blockIdx.x * 256 + threadIdx.x;  // 16,777,216 threads
  {  // states [b*512+t][512] -> xb16 t-major [t*64+b][512]
    unsigned c = gid & 511u, rw = gid >> 9;
    unsigned t = rw >> 6, b = rw & 63u;
    xb16[gid] = f2bf(states[(size_t)(b * 512 + t) * 512 + c]);
  }
  if (gid < 512000u) dout[16777216u + gid] = states[16777216u + gid];  // EXTRA tail
  if (gid < 2359296u) {  // W^T bf16: [l][n(1536)][k(512)]
    unsigned l = gid / 786432u, rem = gid % 786432u;
    unsigned n = rem >> 9, k = rem & 511u;
    float s = (n < 768u) ? Wf[(size_t)(l * 512 + k) * 768 + n]
                         : Wb[(size_t)(l * 512 + k) * 768 + (n - 768u)];
    Wt[gid] = f2bf(s);
  }
  if (gid < 1179648u) {  // U^T bf16: [(dir*3+l)][n(768)][k(256)]
    unsigned g = gid / 196608u, rem = gid % 196608u;
    unsigned dirv = g / 3u, l = g % 3u;
    unsigned n = rem >> 8, k = rem & 255u;
    const float* Usrc = dirv ? Ub : Uf;
    Ut[gid] = f2bf(Usrc[(size_t)(l * 256 + k) * 768 + n]);
  }
  if (gid < 4608u) {  // input bias concat [l][1536]
    unsigned l = gid / 1536u, n = gid % 1536u;
    biasc[gid] = (n < 768u) ? bf_[(l * 2 + 0) * 768 + n]
                            : bb_[(l * 2 + 0) * 768 + (n - 768u)];
  }
  if (gid < 4608u) {  // recurrent bias [(dir*3+l)][768]
    unsigned g = gid / 768u, n = gid % 768u;
    unsigned dirv = g / 3u, l = g % 3u;
    brc[gid] = (dirv ? bb_ : bf_)[(l * 2 + 1) * 768 + n];
  }
  if (gid < 8192u) {  // mask stored as bytes? any word >1 => yes
    if (maskw[gid] > 1u) atomicOr(flag, 1u);
  }
}

// ---- projection GEMM: [32768,512]bf16 x [512,1536]bf16 -> fp16 + bias ----
__global__ __launch_bounds__(256) void proj_gemm(
    const short* __restrict__ A, const short* __restrict__ Bt,
    const float* __restrict__ bias, _Float16* __restrict__ C) {
  __shared__ __align__(16) short As[4096];
  __shared__ __align__(16) short Bs[4096];
  const int tid = threadIdx.x;
  const int wave = tid >> 6, lane = tid & 63;
  const int col = lane & 15, kq = lane >> 4;
  const int wr = wave >> 1, wc = wave & 1;
  const int m0 = blockIdx.x * 128, n0 = blockIdx.y * 128;
  const uint4* Aq = (const uint4*)A;
  const uint4* Bq = (const uint4*)Bt;
  uint4* AsQ = (uint4*)As;
  uint4* BsQ = (uint4*)Bs;
  f32x4 acc[4][4];
#pragma unroll
  for (int i = 0; i < 4; ++i)
#pragma unroll
    for (int j = 0; j < 4; ++j) acc[i][j] = (f32x4){0.f, 0.f, 0.f, 0.f};

  for (int kt = 0; kt < 16; ++kt) {
    const int k8 = kt * 4;  // uint4 offset within a 512-short row
#pragma unroll
    for (int rnd = 0; rnd < 2; ++rnd) {
      int chunk = rnd * 256 + tid;
      int row = chunk >> 2, kc = chunk & 3;
      AsQ[chunk] = Aq[(size_t)(m0 + row) * 64 + k8 + kc];
      BsQ[chunk] = Bq[(size_t)(n0 + row) * 64 + k8 + kc];
    }
    __syncthreads();
    short8 af[4], bfv[4];
#pragma unroll
    for (int i = 0; i < 4; ++i)
      af[i] = *(const short8*)(As + (wr * 64 + i * 16 + col) * 32 + kq * 8);
#pragma unroll
    for (int j = 0; j < 4; ++j)
      bfv[j] = *(const short8*)(Bs + (wc * 64 + j * 16 + col) * 32 + kq * 8);
#pragma unroll
    for (int i = 0; i < 4; ++i)
#pragma unroll
      for (int j = 0; j < 4; ++j)
        acc[i][j] = __builtin_amdgcn_mfma_f32_16x16x32_bf16(af[i], bfv[j], acc[i][j], 0, 0, 0);
    __syncthreads();
  }
#pragma unroll
  for (int j = 0; j < 4; ++j) {
    const int cg = n0 + wc * 64 + j * 16 + col;
    const float bv = bias[cg];
#pragma unroll
    for (int i = 0; i < 4; ++i) {
      const int rb = m0 + wr * 64 + i * 16 + kq * 4;
#pragma unroll
      for (int r = 0; r < 4; ++r)
        C[(size_t)(rb + r) * 1536 + cg] = (_Float16)(acc[i][j][r] + bv);
    }
  }
}

// ---- inter-workgroup barrier (per direction group) ----
__device__ static inline void gbar(unsigned* bar, unsigned target) {
  __syncthreads();
  if (threadIdx.x == 0) {
    __hip_atomic_fetch_add(bar, 1u, __ATOMIC_RELEASE, __HIP_MEMORY_SCOPE_AGENT);
    while (__hip_atomic_load(bar, __ATOMIC_ACQUIRE, __HIP_MEMORY_SCOPE_AGENT) < target)
      __builtin_amdgcn_s_sleep(1);
  }
  __syncthreads();
}

// ---- persistent recurrent kernel: grid = 2*NW blocks of 256 ----
// WG (dir, wg) owns units [wg*16, wg*16+16): U^T B-fragments live in registers.
__global__ __launch_bounds__(256, 1) void gru_rec(
    const _Float16* __restrict__ xp, const short* __restrict__ UtAll,
    const float* __restrict__ brcAll, const unsigned char* __restrict__ mask8,
    const unsigned* __restrict__ flagp, float* __restrict__ h32,
    short* __restrict__ hb16, short* __restrict__ yout, int layer,
    unsigned* __restrict__ bars) {
  const int dir = blockIdx.x >> 4;
  const int wg  = blockIdx.x & 15;
  const int u0  = wg * 16;
  const int tid = threadIdx.x;
  const int wave = tid >> 6, lane = tid & 63;
  const int col = lane & 15, kq = lane >> 4;
  unsigned* bar = bars + (layer * 2 + dir);
  const short* Ut = UtAll + (size_t)(dir * 3 + layer) * 768 * 256;
  const float* brc = brcAll + (dir * 3 + layer) * 768;
  const bool mbyte = (*flagp) != 0u;
  const unsigned* mask32 = (const unsigned*)mask8;

  // preload B fragments: lane holds B[k=kq*8+j][n=u0+col]
  short8 bfrag[3][8];
#pragma unroll
  for (int g = 0; g < 3; ++g)
#pragma unroll
    for (int ks = 0; ks < 8; ++ks)
      bfrag[g][ks] = *(const short8*)(Ut + (size_t)(g * 256 + u0 + col) * 256 + ks * 32 + kq * 8);
  float brv[3];
#pragma unroll
  for (int g = 0; g < 3; ++g) brv[g] = brc[g * 256 + u0 + col];

  float* h32d = h32 + (size_t)dir * 2 * 16384;
  short* hb16d = hb16 + (size_t)dir * 2 * 16384;
#pragma unroll
  for (int q = 0; q < 4; ++q) {  // zero h buf0 slice (this WG's units, all b)
    int idx = q * 256 + tid;
    int b = idx >> 4, u = u0 + (idx & 15);
    h32d[b * 256 + u] = 0.f;
    hb16d[b * 256 + u] = 0;
  }
  gbar(bar, NW * 1u);

  for (int s = 0; s < 512; ++s) {
    const int t = dir ? (511 - s) : s;
    const int rbuf = s & 1, wbuf = rbuf ^ 1;
    const short* hb = hb16d + rbuf * 16384;
    f32x4 acc[3];
    acc[0] = acc[1] = acc[2] = (f32x4){0.f, 0.f, 0.f, 0.f};
#pragma unroll
    for (int ks = 0; ks < 8; ++ks) {
      short8 a = *(const short8*)(hb + (wave * 16 + col) * 256 + ks * 32 + kq * 8);
      acc[0] = __builtin_amdgcn_mfma_f32_16x16x32_bf16(a, bfrag[0][ks], acc[0], 0, 0, 0);
      acc[1] = __builtin_amdgcn_mfma_f32_16x16x32_bf16(a, bfrag[1][ks], acc[1], 0, 0, 0);
      acc[2] = __builtin_amdgcn_mfma_f32_16x16x32_bf16(a, bfrag[2][ks], acc[2], 0, 0, 0);
    }
    const float* h32r = h32d + rbuf * 16384;
    float* h32w = h32d + wbuf * 16384;
    short* hbw = hb16d + wbuf * 16384;
#pragma unroll
    for (int r = 0; r < 4; ++r) {
      const int b = wave * 16 + kq * 4 + r;  // C-layout row
      const size_t xoff = (size_t)(t * 64 + b) * 1536 + (size_t)dir * 768 + u0 + col;
      float xz = (float)xp[xoff], xr = (float)xp[xoff + 256], xh = (float)xp[xoff + 512];
      float hz = acc[0][r] + brv[0];
      float hr = acc[1][r] + brv[1];
      float hh = acc[2][r] + brv[2];
      float z  = 1.f / (1.f + __expf(-(xz + hz)));
      float rr = 1.f / (1.f + __expf(-(xr + hr)));
      float pre = xh + rr * hh;
      float hc = 1.f - 2.f / (__expf(2.f * pre) + 1.f);
      const int hidx = b * 256 + u0 + col;
      float hp = h32r[hidx];
      float hn = z * hp + (1.f - z) * hc;
      bool m = mbyte ? (mask8[b * 512 + t] != 0) : (mask32[b * 512 + t] != 0u);
      hn = m ? hn : hp;
      h32w[hidx] = hn;
      short hnb = f2bf(hn);
      hbw[hidx] = hnb;
      yout[(size_t)(t * 64 + b) * 512 + (size_t)dir * 256 + u0 + col] = hnb;
    }
    gbar(bar, (unsigned)NW * (unsigned)(s + 2));
  }
}

// ---- dropout (JAX threefry partitionable semantics); j == gid (t-major) ----
__global__ __launch_bounds__(256) void drop_k(
    short* __restrict__ xb16, float* __restrict__ dout,
    const int* __restrict__ training, unsigned k0, unsigned k1, int last) {
  const unsigned gid = blockIdx.x * 256 + threadIdx.x;
  float v = bf2f(xb16[gid]);
  unsigned y0, y1;
  tf2x32(k0, k1, 0u, gid, &y0, &y1);
  unsigned bits = y0 ^ y1;
  float u = __uint_as_float((bits >> 9) | 0x3f800000u) - 1.0f;
  bool keep = u < 0.9f;
  int tr = *training;
  float ov = tr ? (keep ? v * (1.0f / 0.9f) : 0.0f) : v;
  if (last) {
    unsigned r = gid >> 9, c = gid & 511u;
    unsigned t = r >> 6, b = r & 63u;
    dout[(size_t)(b * 512 + t) * 512 + c] = ov;
  } else {
    xb16[gid] = f2bf(ov);
  }
}

extern "C" void kernel_launch(void* const* d_in, const int* in_sizes, int n_in,
                              void* d_out, int out_size, void* d_ws, size_t ws_size,
                              hipStream_t stream) {
  (void)in_sizes; (void)n_in; (void)out_size; (void)ws_size;
  const float* states = (const float*)d_in[0];
  const void*  mask   = d_in[1];
  const int*   training = (const int*)d_in[3];
  const float* Wf = (const float*)d_in[4];
  const float* Uf = (const float*)d_in[5];
  const float* bf_ = (const float*)d_in[6];
  const float* Wb = (const float*)d_in[7];
  const float* Ub = (const float*)d_in[8];
  const float* bb_ = (const float*)d_in[9];
  char* ws = (char*)d_ws;

  short* xb16   = (short*)(ws + XB16_OFF);
  _Float16* xp  = (_Float16*)(ws + XP_OFF);
  short* Wt     = (short*)(ws + WT_OFF);
  short* Ut     = (short*)(ws + UT_OFF);
  float* biasc  = (float*)(ws + BIASC_OFF);
  float* brc    = (float*)(ws + BRC_OFF);
  float* h32    = (float*)(ws + H32_OFF);
  short* hb16   = (short*)(ws + HB16_OFF);
  unsigned* bars = (unsigned*)(ws + BAR_OFF);
  unsigned* flag = (unsigned*)(ws + FLAG_OFF);
  float* dout = (float*)d_out;

  // threefry key chain: key(1234); per layer: dkey,sk = split(dkey)
  unsigned d0 = 0u, d1 = 1234u, sk0[3], sk1[3];
  for (int l = 0; l < 3; ++l) {
    unsigned a, b, c, d;
    tf2x32(d0, d1, 0u, 0u, &a, &b);   // new dkey
    tf2x32(d0, d1, 0u, 1u, &c, &d);   // subkey
    sk0[l] = c; sk1[l] = d;
    d0 = a; d1 = b;
  }

  init_k<<<1, 64, 0, stream>>>(bars, flag);
  prep_k<<<65536, 256, 0, stream>>>(states, (const unsigned*)mask, Wf, Uf, bf_,
                                    Wb, Ub, bb_, xb16, dout, Wt, Ut, biasc, brc, flag);
  for (int l = 0; l < 3; ++l) {
    proj_gemm<<<dim3(256, 12), 256, 0, stream>>>(xb16, Wt + (size_t)l * 1536 * 512,
                                                 biasc + l * 1536, xp);
    gru_rec<<<2 * NW, 256, 0, stream>>>(xp, Ut, brc, (const unsigned char*)mask,
                                        flag, h32, hb16, xb16, l, bars);
    drop_k<<<65536, 256, 0, stream>>>(xb16, dout, training, sk0[l], sk1[l], l == 2);
  }
}

// Round 3
// 5247.310 us; speedup vs baseline: 1.8367x; 1.8367x over previous
//
#include <hip/hip_runtime.h>
#include <stdint.h>

typedef __attribute__((ext_vector_type(8))) short short8;
typedef __attribute__((ext_vector_type(4))) float f32x4;

// ---- workspace byte offsets (total ~141.8 MB) ----
#define XB16_OFF  0UL           // bf16 layer input/output [t*64+b][512]   32 MB
#define XP_OFF    33554432UL    // fp16 projections [t*64+b][1536]         96 MB
#define WT_OFF    134217728UL   // bf16 W^T  [3][1536][512]               4.5 MB
#define UT_OFF    138936320UL   // bf16 U^T  [dir*3+l][768][256]         2.25 MB
#define BIASC_OFF 141295616UL   // fp32 input bias [3][1536]
#define BRC_OFF   141314048UL   // fp32 recur bias [dir*3+l][768]
#define FLAG_OFF  141725760UL   // mask-dtype flag

#define HB_STRIDE 264           // 256 + 8 pad (bank-conflict-free, 16B aligned)
#define LDS_BYTES (( (size_t)256*HB_STRIDE + 2*16*HB_STRIDE ) * 2)

// ---- threefry2x32, 20 rounds (jax partitionable mode) ----
__host__ __device__ static inline void tf2x32(unsigned k0, unsigned k1,
                                              unsigned x0, unsigned x1,
                                              unsigned* o0, unsigned* o1) {
  unsigned ks2 = k0 ^ k1 ^ 0x1BD11BDAu;
#define TFR(r) { x0 += x1; x1 = (x1 << (r)) | (x1 >> (32 - (r))); x1 ^= x0; }
  x0 += k0; x1 += k1;
  TFR(13) TFR(15) TFR(26) TFR(6)   x0 += k1;  x1 += ks2 + 1u;
  TFR(17) TFR(29) TFR(16) TFR(24)  x0 += ks2; x1 += k0 + 2u;
  TFR(13) TFR(15) TFR(26) TFR(6)   x0 += k0;  x1 += k1 + 3u;
  TFR(17) TFR(29) TFR(16) TFR(24)  x0 += k1;  x1 += ks2 + 4u;
  TFR(13) TFR(15) TFR(26) TFR(6)   x0 += ks2; x1 += k0 + 5u;
#undef TFR
  *o0 = x0; *o1 = x1;
}

__device__ static inline short f2bf(float f) {  // RNE fp32->bf16
  unsigned u = __float_as_uint(f);
  u = (u + 0x7fffu + ((u >> 16) & 1u)) >> 16;
  return (short)u;
}
__device__ static inline float bf2f(short s) {
  unsigned u = ((unsigned)(unsigned short)s) << 16;
  return __uint_as_float(u);
}

__global__ void init_k(unsigned* flag) {
  if (threadIdx.x == 0) *flag = 0u;
}

// ---- prep: casts, transposes, tail copy, mask dtype detection ----
__global__ __launch_bounds__(256) void prep_k(
    const float* __restrict__ states, const unsigned* __restrict__ maskw,
    const float* __restrict__ Wf, const float* __restrict__ Uf,
    const float* __restrict__ bf_, const float* __restrict__ Wb,
    const float* __restrict__ Ub, const float* __restrict__ bb_,
    short* __restrict__ xb16, float* __restrict__ dout,
    short* __restrict__ Wt, short* __restrict__ Ut,
    float* __restrict__ biasc, float* __restrict__ brc,
    unsigned* __restrict__ flag) {
  const unsigned gid = blockIdx.x * 256 + threadIdx.x;  // 16,777,216 threads
  {  // states [b*512+t][512] -> xb16 t-major [t*64+b][512]
    unsigned c = gid & 511u, rw = gid >> 9;
    unsigned t = rw >> 6, b = rw & 63u;
    xb16[gid] = f2bf(states[(size_t)(b * 512 + t) * 512 + c]);
  }
  if (gid < 512000u) dout[16777216u + gid] = states[16777216u + gid];  // EXTRA tail
  if (gid < 2359296u) {  // W^T bf16: [l][n(1536)][k(512)]
    unsigned l = gid / 786432u, rem = gid % 786432u;
    unsigned n = rem >> 9, k = rem & 511u;
    float s = (n < 768u) ? Wf[(size_t)(l * 512 + k) * 768 + n]
                         : Wb[(size_t)(l * 512 + k) * 768 + (n - 768u)];
    Wt[gid] = f2bf(s);
  }
  if (gid < 1179648u) {  // U^T bf16: [(dir*3+l)][n(768)][k(256)]
    unsigned g = gid / 196608u, rem = gid % 196608u;
    unsigned dirv = g / 3u, l = g % 3u;
    unsigned n = rem >> 8, k = rem & 255u;
    const float* Usrc = dirv ? Ub : Uf;
    Ut[gid] = f2bf(Usrc[(size_t)(l * 256 + k) * 768 + n]);
  }
  if (gid < 4608u) {  // input bias concat [l][1536]
    unsigned l = gid / 1536u, n = gid % 1536u;
    biasc[gid] = (n < 768u) ? bf_[(l * 2 + 0) * 768 + n]
                            : bb_[(l * 2 + 0) * 768 + (n - 768u)];
  }
  if (gid < 4608u) {  // recurrent bias [(dir*3+l)][768]
    unsigned g = gid / 768u, n = gid % 768u;
    unsigned dirv = g / 3u, l = g % 3u;
    brc[gid] = (dirv ? bb_ : bf_)[(l * 2 + 1) * 768 + n];
  }
  if (gid < 8192u) {  // mask stored as bytes? any word >1 => yes
    if (maskw[gid] > 1u) atomicOr(flag, 1u);
  }
}

// ---- projection GEMM: [32768,512]bf16 x [512,1536]bf16 -> fp16 + bias ----
__global__ __launch_bounds__(256) void proj_gemm(
    const short* __restrict__ A, const short* __restrict__ Bt,
    const float* __restrict__ bias, _Float16* __restrict__ C) {
  __shared__ __align__(16) short As[4096];
  __shared__ __align__(16) short Bs[4096];
  const int tid = threadIdx.x;
  const int wave = tid >> 6, lane = tid & 63;
  const int col = lane & 15, kq = lane >> 4;
  const int wr = wave >> 1, wc = wave & 1;
  const int m0 = blockIdx.x * 128, n0 = blockIdx.y * 128;
  const uint4* Aq = (const uint4*)A;
  const uint4* Bq = (const uint4*)Bt;
  uint4* AsQ = (uint4*)As;
  uint4* BsQ = (uint4*)Bs;
  f32x4 acc[4][4];
#pragma unroll
  for (int i = 0; i < 4; ++i)
#pragma unroll
    for (int j = 0; j < 4; ++j) acc[i][j] = (f32x4){0.f, 0.f, 0.f, 0.f};

  for (int kt = 0; kt < 16; ++kt) {
    const int k8 = kt * 4;
#pragma unroll
    for (int rnd = 0; rnd < 2; ++rnd) {
      int chunk = rnd * 256 + tid;
      int row = chunk >> 2, kc = chunk & 3;
      AsQ[chunk] = Aq[(size_t)(m0 + row) * 64 + k8 + kc];
      BsQ[chunk] = Bq[(size_t)(n0 + row) * 64 + k8 + kc];
    }
    __syncthreads();
    short8 af[4], bfv[4];
#pragma unroll
    for (int i = 0; i < 4; ++i)
      af[i] = *(const short8*)(As + (wr * 64 + i * 16 + col) * 32 + kq * 8);
#pragma unroll
    for (int j = 0; j < 4; ++j)
      bfv[j] = *(const short8*)(Bs + (wc * 64 + j * 16 + col) * 32 + kq * 8);
#pragma unroll
    for (int i = 0; i < 4; ++i)
#pragma unroll
      for (int j = 0; j < 4; ++j)
        acc[i][j] = __builtin_amdgcn_mfma_f32_16x16x32_bf16(af[i], bfv[j], acc[i][j], 0, 0, 0);
    __syncthreads();
  }
#pragma unroll
  for (int j = 0; j < 4; ++j) {
    const int cg = n0 + wc * 64 + j * 16 + col;
    const float bv = bias[cg];
#pragma unroll
    for (int i = 0; i < 4; ++i) {
      const int rb = m0 + wr * 64 + i * 16 + kq * 4;
#pragma unroll
      for (int r = 0; r < 4; ++r)
        C[(size_t)(rb + r) * 1536 + cg] = (_Float16)(acc[i][j][r] + bv);
    }
  }
}

// ---- LDS-local recurrent kernel: grid = 8 blocks (2 dir x 4 batch slices) ----
// WG owns 16 batch rows + ALL 256 units. h in LDS; sync = __syncthreads only.
// Wave w owns units [w*32, w*32+32): z/r U^T frags in VGPRs, h-gate U^T in LDS.
__global__ __launch_bounds__(512, 2) void gru_lds(
    const _Float16* __restrict__ xp, const short* __restrict__ UtAll,
    const float* __restrict__ brcAll, const unsigned char* __restrict__ mask8,
    const unsigned* __restrict__ flagp, short* __restrict__ yout, int layer) {
  extern __shared__ short lds[];
  short* hB = lds;                          // [256][HB_STRIDE] h-gate U^T
  short* hbuf = lds + 256 * HB_STRIDE;      // [2][16][HB_STRIDE] h state (bf16)

  const int bid = blockIdx.x;
  const int dir = bid >> 2;
  const int b0 = (bid & 3) * 16;
  const int tid = threadIdx.x;
  const int wave = tid >> 6, lane = tid & 63;
  const int col = lane & 15, quad = lane >> 4;
  const short* Ut = UtAll + (size_t)(dir * 3 + layer) * 768 * 256;
  const float* brc = brcAll + (dir * 3 + layer) * 768;
  const bool mbyte = (*flagp) != 0u;
  const unsigned* mask32 = (const unsigned*)mask8;

  // stage h-gate U^T [256][256] into padded LDS
  const short* Uth = Ut + 512 * 256;
  for (int c = tid; c < 8192; c += 512) {
    int row = c >> 5, q = c & 31;
    *(uint4*)(hB + row * HB_STRIDE + q * 8) = *(const uint4*)(Uth + row * 256 + q * 8);
  }
  for (int i = tid; i < 2 * 16 * HB_STRIDE; i += 512) hbuf[i] = 0;

  // resident z/r B fragments: lane holds B[k=quad*8+j][n=u]
  short8 zB[2][8], rB[2][8];
  float brz[2], brr[2], brh[2];
#pragma unroll
  for (int g = 0; g < 2; ++g) {
    const int u = wave * 32 + g * 16 + col;
#pragma unroll
    for (int ks = 0; ks < 8; ++ks) {
      zB[g][ks] = *(const short8*)(Ut + (size_t)u * 256 + ks * 32 + quad * 8);
      rB[g][ks] = *(const short8*)(Ut + (size_t)(256 + u) * 256 + ks * 32 + quad * 8);
    }
    brz[g] = brc[u]; brr[g] = brc[256 + u]; brh[g] = brc[512 + u];
  }
  float hp[2][4] = {{0.f, 0.f, 0.f, 0.f}, {0.f, 0.f, 0.f, 0.f}};
  __syncthreads();

  for (int s = 0; s < 512; ++s) {
    const int t = dir ? (511 - s) : s;
    // xp loads — issue early, consumed in epilogue
    float xpv[2][3][4];
#pragma unroll
    for (int g = 0; g < 2; ++g) {
      const int u = wave * 32 + g * 16 + col;
#pragma unroll
      for (int r = 0; r < 4; ++r) {
        const size_t base = (size_t)(t * 64 + b0 + quad * 4 + r) * 1536 + (size_t)dir * 768 + u;
        xpv[g][0][r] = (float)xp[base];
        xpv[g][1][r] = (float)xp[base + 256];
        xpv[g][2][r] = (float)xp[base + 512];
      }
    }
    unsigned mv[4];
#pragma unroll
    for (int r = 0; r < 4; ++r) {
      const int gb = b0 + quad * 4 + r;
      mv[r] = mbyte ? (unsigned)mask8[gb * 512 + t] : mask32[gb * 512 + t];
    }

    const short* hrd = hbuf + (s & 1) * (16 * HB_STRIDE);
    f32x4 az[2], ar[2], ah[2];
    az[0] = az[1] = ar[0] = ar[1] = ah[0] = ah[1] = (f32x4){0.f, 0.f, 0.f, 0.f};
#pragma unroll
    for (int ks = 0; ks < 8; ++ks) {
      short8 a = *(const short8*)(hrd + col * HB_STRIDE + ks * 32 + quad * 8);
      short8 hb0 = *(const short8*)(hB + (wave * 32 + col) * HB_STRIDE + ks * 32 + quad * 8);
      short8 hb1 = *(const short8*)(hB + (wave * 32 + 16 + col) * HB_STRIDE + ks * 32 + quad * 8);
      az[0] = __builtin_amdgcn_mfma_f32_16x16x32_bf16(a, zB[0][ks], az[0], 0, 0, 0);
      az[1] = __builtin_amdgcn_mfma_f32_16x16x32_bf16(a, zB[1][ks], az[1], 0, 0, 0);
      ar[0] = __builtin_amdgcn_mfma_f32_16x16x32_bf16(a, rB[0][ks], ar[0], 0, 0, 0);
      ar[1] = __builtin_amdgcn_mfma_f32_16x16x32_bf16(a, rB[1][ks], ar[1], 0, 0, 0);
      ah[0] = __builtin_amdgcn_mfma_f32_16x16x32_bf16(a, hb0, ah[0], 0, 0, 0);
      ah[1] = __builtin_amdgcn_mfma_f32_16x16x32_bf16(a, hb1, ah[1], 0, 0, 0);
    }

    short* hwr = hbuf + ((s & 1) ^ 1) * (16 * HB_STRIDE);
#pragma unroll
    for (int g = 0; g < 2; ++g) {
      const int u = wave * 32 + g * 16 + col;
#pragma unroll
      for (int r = 0; r < 4; ++r) {
        float hz = az[g][r] + brz[g];
        float hr = ar[g][r] + brr[g];
        float hh = ah[g][r] + brh[g];
        float z  = 1.f / (1.f + __expf(-(xpv[g][0][r] + hz)));
        float rr = 1.f / (1.f + __expf(-(xpv[g][1][r] + hr)));
        float pre = xpv[g][2][r] + rr * hh;
        float hc = 1.f - 2.f / (__expf(2.f * pre) + 1.f);
        float hpv = hp[g][r];
        float hn = z * hpv + (1.f - z) * hc;
        hn = mv[r] ? hn : hpv;
        hp[g][r] = hn;
        const int b = quad * 4 + r;
        short hnb = f2bf(hn);
        hwr[b * HB_STRIDE + u] = hnb;
        yout[(size_t)(t * 64 + b0 + b) * 512 + (size_t)dir * 256 + u] = hnb;
      }
    }
    __syncthreads();
  }
}

// ---- dropout (JAX threefry partitionable); j == gid (t-major) ----
__global__ __launch_bounds__(256) void drop_k(
    short* __restrict__ xb16, float* __restrict__ dout,
    const int* __restrict__ training, unsigned k0, unsigned k1, int last) {
  const unsigned gid = blockIdx.x * 256 + threadIdx.x;
  float v = bf2f(xb16[gid]);
  unsigned y0, y1;
  tf2x32(k0, k1, 0u, gid, &y0, &y1);
  unsigned bits = y0 ^ y1;
  float u = __uint_as_float((bits >> 9) | 0x3f800000u) - 1.0f;
  bool keep = u < 0.9f;
  int tr = *training;
  float ov = tr ? (keep ? v * (1.0f / 0.9f) : 0.0f) : v;
  if (last) {
    unsigned r = gid >> 9, c = gid & 511u;
    unsigned t = r >> 6, b = r & 63u;
    dout[(size_t)(b * 512 + t) * 512 + c] = ov;
  } else {
    xb16[gid] = f2bf(ov);
  }
}

extern "C" void kernel_launch(void* const* d_in, const int* in_sizes, int n_in,
                              void* d_out, int out_size, void* d_ws, size_t ws_size,
                              hipStream_t stream) {
  (void)in_sizes; (void)n_in; (void)out_size; (void)ws_size;
  const float* states = (const float*)d_in[0];
  const void*  mask   = d_in[1];
  const int*   training = (const int*)d_in[3];
  const float* Wf = (const float*)d_in[4];
  const float* Uf = (const float*)d_in[5];
  const float* bf_ = (const float*)d_in[6];
  const float* Wb = (const float*)d_in[7];
  const float* Ub = (const float*)d_in[8];
  const float* bb_ = (const float*)d_in[9];
  char* ws = (char*)d_ws;

  short* xb16   = (short*)(ws + XB16_OFF);
  _Float16* xp  = (_Float16*)(ws + XP_OFF);
  short* Wt     = (short*)(ws + WT_OFF);
  short* Ut     = (short*)(ws + UT_OFF);
  float* biasc  = (float*)(ws + BIASC_OFF);
  float* brc    = (float*)(ws + BRC_OFF);
  unsigned* flag = (unsigned*)(ws + FLAG_OFF);
  float* dout = (float*)d_out;

  // allow >64KB dynamic LDS for gru_lds (idempotent; not a stream op)
  hipFuncSetAttribute((const void*)gru_lds,
                      hipFuncAttributeMaxDynamicSharedMemorySize, (int)LDS_BYTES);

  // threefry key chain: key(1234); per layer: dkey,sk = split(dkey)
  unsigned d0 = 0u, d1 = 1234u, sk0[3], sk1[3];
  for (int l = 0; l < 3; ++l) {
    unsigned a, b, c, d;
    tf2x32(d0, d1, 0u, 0u, &a, &b);   // new dkey
    tf2x32(d0, d1, 0u, 1u, &c, &d);   // subkey
    sk0[l] = c; sk1[l] = d;
    d0 = a; d1 = b;
  }

  init_k<<<1, 64, 0, stream>>>(flag);
  prep_k<<<65536, 256, 0, stream>>>(states, (const unsigned*)mask, Wf, Uf, bf_,
                                    Wb, Ub, bb_, xb16, dout, Wt, Ut, biasc, brc, flag);
  for (int l = 0; l < 3; ++l) {
    proj_gemm<<<dim3(256, 12), 256, 0, stream>>>(xb16, Wt + (size_t)l * 1536 * 512,
                                                 biasc + l * 1536, xp);
    gru_lds<<<8, 512, LDS_BYTES, stream>>>(xp, Ut, brc, (const unsigned char*)mask,
                                           flag, xb16, l);
    drop_k<<<65536, 256, 0, stream>>>(xb16, dout, training, sk0[l], sk1[l], l == 2);
  }
}